// Round 9
// baseline (238.693 us; speedup 1.0000x reference)
//
#include <hip/hip_runtime.h>
#include <hip/hip_bf16.h>
#include <stdint.h>

// PixproLoss: out = -(sum_masked cos_sim / count_mask), B=2048, C=256, P=49.
// R11 = R3/R6-verified numerics with the staging done by global_load_lds DMA:
//   - f32 linear stage (49 x 1KB chunks, width=16, zero VALU, zero scatter;
//     R10's per-element transpose tax -- magic-div + f2bf + conflicted
//     ds_write_u16 per element -- was the 86us limiter, ~1.03e7 conflict cyc)
//   - ONE 50KB stage buffer reused m -> b (63.4 KB LDS total)
//   - A-frags built from row-major f32 LDS via scalar ds_read_b32 (row stride
//     49 dwords; 49 mod 32 = 17 coprime -> lanes spread across banks)
//   - norms fp32 from the same values (R3/R6-identical arithmetic, absmax 0.0)
//   - MFMA (m2 = maskS x m-frags), epilogue, final: R6 code verbatim,
//     with epilogue b reads from LDS instead of fragmented global.
// Lessons: no per-element scatter; no LDS atomics; loads/DMA consumed at the
// next barrier; no cross-barrier reg prefetch (except A-mask regs, proven);
// linear-dest-only for global_load_lds (guide #21).

typedef __attribute__((ext_vector_type(8))) short short8;
typedef __attribute__((ext_vector_type(4))) float floatx4;

#define P 49
#define CP 12544           // C*P
#define NMASK 2401         // P*P
#define MS_STRIDE 72       // maskS LDS row stride (bf16): 64 data + 8 pad

#define GLL(gaddr, laddr) __builtin_amdgcn_global_load_lds( \
    (const __attribute__((address_space(1))) uint32_t*)(gaddr), \
    (__attribute__((address_space(3))) uint32_t*)(laddr), 16, 0, 0)

__device__ __forceinline__ short8 cvt8(float4 a, float4 b) {
  union { __hip_bfloat162 h2; short s2[2]; } t;
  short8 r;
  t.h2 = __float22bfloat162_rn(make_float2(a.x, a.y)); r[0] = t.s2[0]; r[1] = t.s2[1];
  t.h2 = __float22bfloat162_rn(make_float2(a.z, a.w)); r[2] = t.s2[0]; r[3] = t.s2[1];
  t.h2 = __float22bfloat162_rn(make_float2(b.x, b.y)); r[4] = t.s2[0]; r[5] = t.s2[1];
  t.h2 = __float22bfloat162_rn(make_float2(b.z, b.w)); r[6] = t.s2[0]; r[7] = t.s2[1];
  return r;
}

__global__ __launch_bounds__(512, 4) void pixpro_main(
    const float* __restrict__ base, const float* __restrict__ moment,
    const int* __restrict__ A, float* __restrict__ ws_num, float* __restrict__ ws_cnt)
{
  __shared__ __align__(16) float stage[CP];                    // 50176 B, m then b
  __shared__ __align__(16) uint16_t maskS[P * MS_STRIDE];      // 7056 B
  __shared__ __align__(16) float normredW[8 * 64];             // 2048 B
  __shared__ __align__(16) float SQred[8 * 4 * 16 * 2];        // 4096 B
  __shared__ float cntred[8];                                  // total ~63.4 KB

  const int b    = blockIdx.x;
  const int tid  = threadIdx.x;
  const int lane = tid & 63;
  const int wv   = tid >> 6;          // 0..7
  const int mrow = lane & 15;
  const int kgrp = (lane >> 4) & 3;

  const float* gb = base   + (size_t)b * CP;
  const float* gm = moment + (size_t)b * CP;
  const int*   gA = A      + (size_t)b * NMASK;

  // ---- stage m: 49 x 1KB DMA chunks (wave wv owns chunks wv, wv+8, ...) ----
  {
    const uint32_t* gsrc = (const uint32_t*)gm;
    uint32_t* ldst = (uint32_t*)stage;
    #pragma unroll
    for (int t = 0; t < 6; ++t) {
      const int ch = wv + t * 8;
      GLL(gsrc + ch * 256 + lane * 4, ldst + ch * 256);
    }
    if (wv == 0) GLL(gsrc + 48 * 256 + lane * 4, ldst + 48 * 256);
  }

  // ---- A-mask loads into regs (drain at barrier A; consumed post-B) ----
  const bool btask = tid < P * 8;     // 392 tasks: p = tid>>3, q-group = tid&7
  const int  bp    = tid >> 3;
  const int  bqg   = tid & 7;
  const int  bq0   = bqg * 8;
  int bmask[8];
  #pragma unroll
  for (int j = 0; j < 8; ++j) bmask[j] = 0;
  if (btask) {
    const int* Ar = gA + bp * P + bq0;
    if (bqg <= 5) {                   // q <= 47, fully valid & in-bounds
      int4 u0 = *(const int4*)(Ar);
      int4 u1 = *(const int4*)(Ar + 4);
      bmask[0] = u0.x; bmask[1] = u0.y; bmask[2] = u0.z; bmask[3] = u0.w;
      bmask[4] = u1.x; bmask[5] = u1.y; bmask[6] = u1.z; bmask[7] = u1.w;
    } else if (bqg == 6) {            // only q=48 valid (scalar avoids OOB)
      bmask[0] = Ar[0];
    }
  }
  __syncthreads();   // barrier A: m in LDS (DMA drained), bmask in regs

  // ---- frag build from row-major f32 LDS + fp32 norms (R3/R6 arithmetic) ----
  // A-frag layout: lane -> A[m = mrow][k = kgrp*8 + j]; m = c-within-tile, k = q.
  short8 afrag[2][2];                 // [cti][kt], bf16
  float s0[8], s1[8];
  #pragma unroll
  for (int j = 0; j < 8; ++j) { s0[j] = 0.f; s1[j] = 0.f; }

  #pragma unroll
  for (int cti = 0; cti < 2; ++cti) {
    const int c = (2 * wv + cti) * 16 + mrow;
    const float* row = &stage[c * 49];
    float av[8], bw[8];
    #pragma unroll
    for (int j = 0; j < 8; ++j) av[j] = row[kgrp * 8 + j];   // q = kgrp*8+j
    if (kgrp < 2) {
      #pragma unroll
      for (int j = 0; j < 8; ++j) bw[j] = row[32 + kgrp * 8 + j];
    } else if (kgrp == 2) {
      bw[0] = row[48];
      #pragma unroll
      for (int j = 1; j < 8; ++j) bw[j] = 0.f;
    } else {
      #pragma unroll
      for (int j = 0; j < 8; ++j) bw[j] = 0.f;
    }
    #pragma unroll
    for (int j = 0; j < 8; ++j) {
      s0[j] = fmaf(av[j], av[j], s0[j]);
      s1[j] = fmaf(bw[j], bw[j], s1[j]);
    }
    afrag[cti][0] = cvt8(make_float4(av[0], av[1], av[2], av[3]),
                         make_float4(av[4], av[5], av[6], av[7]));
    afrag[cti][1] = cvt8(make_float4(bw[0], bw[1], bw[2], bw[3]),
                         make_float4(bw[4], bw[5], bw[6], bw[7]));
  }

  // full-wave norm reduce over mrow (xor 1,2,4,8); 4 holders/wave
  #pragma unroll
  for (int j = 0; j < 8; ++j) {
    s0[j] += __shfl_xor(s0[j], 1); s0[j] += __shfl_xor(s0[j], 2);
    s0[j] += __shfl_xor(s0[j], 4); s0[j] += __shfl_xor(s0[j], 8);
    s1[j] += __shfl_xor(s1[j], 1); s1[j] += __shfl_xor(s1[j], 2);
    s1[j] += __shfl_xor(s1[j], 4); s1[j] += __shfl_xor(s1[j], 8);
  }
  if (mrow == 0) {
    float* nb_ = &normredW[wv * 64 + kgrp * 8];
    *(float4*)(nb_ + 0)  = make_float4(s0[0], s0[1], s0[2], s0[3]);
    *(float4*)(nb_ + 4)  = make_float4(s0[4], s0[5], s0[6], s0[7]);
    *(float4*)(nb_ + 32) = make_float4(s1[0], s1[1], s1[2], s1[3]);
    *(float4*)(nb_ + 36) = make_float4(s1[4], s1[5], s1[6], s1[7]);
  }
  __syncthreads();   // barrier B: all m-reads done, normredW visible

  // ---- stage b into the SAME buffer (issued now, drained at barrier C) ----
  {
    const uint32_t* gsrc = (const uint32_t*)gb;
    uint32_t* ldst = (uint32_t*)stage;
    #pragma unroll
    for (int t = 0; t < 6; ++t) {
      const int ch = wv + t * 8;
      GLL(gsrc + ch * 256 + lane * 4, ldst + ch * 256);
    }
    if (wv == 0) GLL(gsrc + 48 * 256 + lane * 4, ldst + 48 * 256);
  }

  // ---- maskS build with distributed inv_nm (R6-verified) ----
  int cntpart = 0;
  if (btask) {
    float4 a0 = make_float4(0.f, 0.f, 0.f, 0.f);
    float4 a1 = make_float4(0.f, 0.f, 0.f, 0.f);
    #pragma unroll
    for (int w = 0; w < 8; ++w) {
      const float* nr = &normredW[w * 64 + bq0];
      float4 u0 = *(const float4*)(nr);
      float4 u1 = *(const float4*)(nr + 4);
      a0.x += u0.x; a0.y += u0.y; a0.z += u0.z; a0.w += u0.w;
      a1.x += u1.x; a1.y += u1.y; a1.z += u1.z; a1.w += u1.w;
    }
    float4 f0, f1;
    f0.x = bmask[0] ? (1.0f / fmaxf(sqrtf(a0.x), 1e-6f)) : 0.f;
    f0.y = bmask[1] ? (1.0f / fmaxf(sqrtf(a0.y), 1e-6f)) : 0.f;
    f0.z = bmask[2] ? (1.0f / fmaxf(sqrtf(a0.z), 1e-6f)) : 0.f;
    f0.w = bmask[3] ? (1.0f / fmaxf(sqrtf(a0.w), 1e-6f)) : 0.f;
    f1.x = bmask[4] ? (1.0f / fmaxf(sqrtf(a1.x), 1e-6f)) : 0.f;
    f1.y = bmask[5] ? (1.0f / fmaxf(sqrtf(a1.y), 1e-6f)) : 0.f;
    f1.z = bmask[6] ? (1.0f / fmaxf(sqrtf(a1.z), 1e-6f)) : 0.f;
    f1.w = bmask[7] ? (1.0f / fmaxf(sqrtf(a1.w), 1e-6f)) : 0.f;
    #pragma unroll
    for (int j = 0; j < 8; ++j) cntpart += bmask[j];
    *(short8*)&maskS[bp * MS_STRIDE + bq0] = cvt8(f0, f1);
  }
  __syncthreads();   // barrier C: b in LDS, maskS visible

  // ---- MFMA: m2 tiles; B-frag: lane -> B[k = kgrp*8+j][n = mrow] ----
  const int pbase[4] = {0, 16, 32, 33};   // tile 3 = rows 33..48 (dedup in epilogue)
  floatx4 acc[2][4];
  #pragma unroll
  for (int i = 0; i < 2; ++i)
    #pragma unroll
    for (int j = 0; j < 4; ++j) acc[i][j] = (floatx4){0.f, 0.f, 0.f, 0.f};

  #pragma unroll
  for (int kt = 0; kt < 2; ++kt) {
    short8 bfr[4];
    #pragma unroll
    for (int pt = 0; pt < 4; ++pt)
      bfr[pt] = *(const short8*)&maskS[(pbase[pt] + mrow) * MS_STRIDE + kt * 32 + kgrp * 8];
    #pragma unroll
    for (int cti = 0; cti < 2; ++cti)
      #pragma unroll
      for (int pt = 0; pt < 4; ++pt)
        acc[cti][pt] = __builtin_amdgcn_mfma_f32_16x16x32_bf16(afrag[cti][kt], bfr[pt], acc[cti][pt], 0, 0, 0);
  }

  // ---- Epilogue: S[p] = sum_c b[c,p]*m2[c,p], Q[p] = sum_c b[c,p]^2 ----
  // b read from LDS (f32, row-major): 16 scalar ds_read_b32 per lane.
  float S[4] = {0.f, 0.f, 0.f, 0.f}, Qn[4] = {0.f, 0.f, 0.f, 0.f};
  #pragma unroll
  for (int cti = 0; cti < 2; ++cti) {
    float bv[4][4];
    #pragma unroll
    for (int pt = 0; pt < 4; ++pt) {
      const int pd = pbase[pt] + mrow;
      const bool pv = (pt < 3) || (mrow == 15);   // dedup rows 33..47 of tile 3
      #pragma unroll
      for (int r = 0; r < 4; ++r) {
        const int c = (2 * wv + cti) * 16 + kgrp * 4 + r;
        float v = stage[c * 49 + pd];
        bv[pt][r] = pv ? v : 0.f;
      }
    }
    #pragma unroll
    for (int pt = 0; pt < 4; ++pt)
      #pragma unroll
      for (int r = 0; r < 4; ++r) {
        S[pt]  = fmaf(bv[pt][r], acc[cti][pt][r], S[pt]);
        Qn[pt] = fmaf(bv[pt][r], bv[pt][r], Qn[pt]);
      }
  }

  // reduce over kgrp (lane bits 4,5)
  #pragma unroll
  for (int pt = 0; pt < 4; ++pt) {
    S[pt]  += __shfl_xor(S[pt], 16);  S[pt]  += __shfl_xor(S[pt], 32);
    Qn[pt] += __shfl_xor(Qn[pt], 16); Qn[pt] += __shfl_xor(Qn[pt], 32);
  }
  float cntf = (float)cntpart;
  #pragma unroll
  for (int off = 32; off > 0; off >>= 1) cntf += __shfl_xor(cntf, off);

  if (lane < 16) {
    #pragma unroll
    for (int pt = 0; pt < 4; ++pt)
      *(float2*)&SQred[((wv * 4 + pt) * 16 + mrow) * 2] = make_float2(S[pt], Qn[pt]);
  }
  if (lane == 0) cntred[wv] = cntf;
  __syncthreads();   // barrier D

  // ---- final: num = sum_p S[p]/max(||b_p||,eps); one wave ----
  if (tid < 64) {
    float num = 0.f, cc = 0.f;
    if (tid < P) {
      const int pt = tid >> 4;                       // 48 -> 3
      const int mr = (pt == 3) ? 15 : (tid & 15);
      float Sp = 0.f, Qp = 0.f;
      #pragma unroll
      for (int w = 0; w < 8; ++w) {
        const int idx = ((w * 4 + pt) * 16 + mr) * 2;
        Sp += SQred[idx];
        Qp += SQred[idx + 1];
      }
      num = Sp * (1.0f / fmaxf(sqrtf(Qp), 1e-6f));
    }
    if (tid < 8) cc = cntred[tid];
    #pragma unroll
    for (int off = 32; off > 0; off >>= 1) {
      num += __shfl_xor(num, off);
      cc  += __shfl_xor(cc, off);
    }
    if (tid == 0) { ws_num[b] = num; ws_cnt[b] = cc; }
  }
}

__global__ __launch_bounds__(256) void pixpro_reduce(
    const float* __restrict__ ws_num, const float* __restrict__ ws_cnt,
    float* __restrict__ out)
{
  __shared__ float rn[4], rc[4];
  float n = 0.f, c = 0.f;
  for (int i = threadIdx.x; i < 2048; i += 256) { n += ws_num[i]; c += ws_cnt[i]; }
  #pragma unroll
  for (int off = 32; off > 0; off >>= 1) {
    n += __shfl_down(n, off, 64);
    c += __shfl_down(c, off, 64);
  }
  const int wv = threadIdx.x >> 6, lane = threadIdx.x & 63;
  if (lane == 0) { rn[wv] = n; rc[wv] = c; }
  __syncthreads();
  if (threadIdx.x == 0) {
    float N = rn[0] + rn[1] + rn[2] + rn[3];
    float D = rc[0] + rc[1] + rc[2] + rc[3];
    out[0] = -(N / D);
  }
}

extern "C" void kernel_launch(void* const* d_in, const int* in_sizes, int n_in,
                              void* d_out, int out_size, void* d_ws, size_t ws_size,
                              hipStream_t stream) {
  const float* base   = (const float*)d_in[0];
  const float* moment = (const float*)d_in[1];
  const int*   A      = (const int*)d_in[2];
  float* ws_num = (float*)d_ws;          // 2048 floats
  float* ws_cnt = ws_num + 2048;         // 2048 floats
  pixpro_main<<<2048, 512, 0, stream>>>(base, moment, A, ws_num, ws_cnt);
  pixpro_reduce<<<1, 256, 0, stream>>>(ws_num, ws_cnt, (float*)d_out);
}